// Round 1
// baseline (214.115 us; speedup 1.0000x reference)
//
#include <hip/hip_runtime.h>

#define NNODES 468
#define NT 128        // output nodes per tile
#define ROWS 146      // NT + 2*9 halo
#define ROWS_P 152    // padded to RG*RPT
#define KT 64         // k-tile
#define DOB 128       // output-column block
#define CG 32         // DOB/4 column groups
#define RG 8          // 256/CG row groups
#define RPT 19        // ROWS_P / RG

// ---------------------------------------------------------------------------
// Node encoder: X0[b,n,c] = sum_t L[b, n*3+t] * We[t,c] + be[c]
// ---------------------------------------------------------------------------
__global__ __launch_bounds__(256) void enc_kernel(
    const float* __restrict__ L, const float* __restrict__ We,
    const float* __restrict__ be, float* __restrict__ X0)
{
    int g = blockIdx.x * 256 + threadIdx.x;
    if (g >= 128 * NNODES * 64) return;
    int c   = g & 63;
    int row = g >> 6;          // b*468 + n
    float l0 = L[row * 3 + 0];
    float l1 = L[row * 3 + 1];
    float l2 = L[row * 3 + 2];
    X0[g] = be[c] + l0 * We[c] + l1 * We[64 + c] + l2 * We[128 + c];
}

// ---------------------------------------------------------------------------
// Fused GCN layer: Xout = relu( A @ (Xin @ W) + bias )
// A is the banded normalized adjacency (|i-j|<=9 incl. self-loop).
// Grid: (4 node tiles, 128 batches, D_OUT_TOTAL/128 col blocks). 256 threads.
// ---------------------------------------------------------------------------
template<int D_IN>
__global__ __launch_bounds__(256, 2) void gcn_layer(
    const float* __restrict__ Xin, const float* __restrict__ W,
    const float* __restrict__ bias, float* __restrict__ Xout,
    int d_out_total)
{
    // smem layout: phase A/B: Xs[ROWS_P][KT] then Ws[KT][DOB]
    //              phase C  : Hs[ROWS_P][DOB]   (overlays both)
    __shared__ __align__(16) float smem[ROWS_P * DOB];   // 19456 floats = 76 KiB
    __shared__ float dinvs[ROWS_P];

    float* Xs = smem;                       // [ROWS_P][KT]
    float* Ws = smem + ROWS_P * KT;         // [KT][DOB]

    const int tid  = threadIdx.x;
    const int tile = blockIdx.x;
    const int b    = blockIdx.y;
    const int cb   = blockIdx.z;
    const int n0   = tile * NT;
    const int c0   = cb * DOB;

    // degree^-1/2 for every staged row (closed form; clamp keeps it finite)
    if (tid < ROWS_P) {
        int node = n0 - 9 + tid;
        int lo = node - 9; if (lo < 0) lo = 0;
        int hi = node + 9; if (hi > NNODES - 1) hi = NNODES - 1;
        int deg = hi - lo + 1; if (deg < 1) deg = 1;
        dinvs[tid] = 1.0f / sqrtf((float)deg);
    }

    const int cx = tid % CG;   // column group (4 cols each)
    const int ry = tid / CG;   // row group

    float acc[RPT][4];
    #pragma unroll
    for (int i = 0; i < RPT; ++i) { acc[i][0] = acc[i][1] = acc[i][2] = acc[i][3] = 0.f; }

    const float* Xb = Xin + (size_t)b * NNODES * D_IN;

    for (int k0 = 0; k0 < D_IN; k0 += KT) {
        __syncthreads();   // protect previous iteration's reads (no-op first iter)
        // stage Xs: rows n0-9 .. n0-9+ROWS_P-1, cols k0..k0+63 (zero pad OOR)
        for (int idx = tid; idx < ROWS_P * (KT / 4); idx += 256) {
            int r  = idx / (KT / 4);
            int c4 = (idx % (KT / 4)) * 4;
            int node = n0 - 9 + r;
            float4 v = make_float4(0.f, 0.f, 0.f, 0.f);
            if (r < ROWS && node >= 0 && node < NNODES)
                v = *(const float4*)(Xb + (size_t)node * D_IN + k0 + c4);
            *(float4*)(Xs + r * KT + c4) = v;
        }
        // stage Ws: W[k0+kk][c0 + c]
        for (int idx = tid; idx < KT * (DOB / 4); idx += 256) {
            int kk = idx / (DOB / 4);
            int c4 = (idx % (DOB / 4)) * 4;
            *(float4*)(Ws + kk * DOB + c4) =
                *(const float4*)(W + (size_t)(k0 + kk) * d_out_total + c0 + c4);
        }
        __syncthreads();

        for (int kk = 0; kk < KT; kk += 4) {
            float4 xv[RPT];
            #pragma unroll
            for (int i = 0; i < RPT; ++i)
                xv[i] = *(const float4*)(Xs + (ry + RG * i) * KT + kk);
            #pragma unroll
            for (int q = 0; q < 4; ++q) {
                float4 w = *(const float4*)(Ws + (kk + q) * DOB + cx * 4);
                #pragma unroll
                for (int i = 0; i < RPT; ++i) {
                    float x = (q == 0) ? xv[i].x : (q == 1) ? xv[i].y
                            : (q == 2) ? xv[i].z : xv[i].w;
                    acc[i][0] += x * w.x;
                    acc[i][1] += x * w.y;
                    acc[i][2] += x * w.z;
                    acc[i][3] += x * w.w;
                }
            }
        }
    }

    __syncthreads();   // all reads of Xs/Ws done before Hs overlays them
    float* Hs = smem;  // [ROWS_P][DOB]
    #pragma unroll
    for (int i = 0; i < RPT; ++i)
        *(float4*)(Hs + (ry + RG * i) * DOB + cx * 4) =
            make_float4(acc[i][0], acc[i][1], acc[i][2], acc[i][3]);
    __syncthreads();

    // Band aggregation: thread owns 16 consecutive output nodes x 4 cols.
    // Sweep rows once (rolling window): row r feeds nodes oi in [r-18, r].
    const int oi0 = ry * 16;
    float oacc[16][4];
    #pragma unroll
    for (int i = 0; i < 16; ++i) { oacc[i][0] = oacc[i][1] = oacc[i][2] = oacc[i][3] = 0.f; }
    float dinv_i[16];
    #pragma unroll
    for (int i = 0; i < 16; ++i) dinv_i[i] = dinvs[oi0 + i + 9];

    #pragma unroll
    for (int rr = 0; rr < 34; ++rr) {
        int r = oi0 + rr;
        float4 h = *(const float4*)(Hs + r * DOB + cx * 4);
        float dr = dinvs[r];
        #pragma unroll
        for (int i = 0; i < 16; ++i) {
            if (i >= rr - 18 && i <= rr) {   // compile-time tap validity
                float cf = dinv_i[i] * dr;
                oacc[i][0] += cf * h.x;
                oacc[i][1] += cf * h.y;
                oacc[i][2] += cf * h.z;
                oacc[i][3] += cf * h.w;
            }
        }
    }

    const float4 bv = *(const float4*)(bias + c0 + cx * 4);
    #pragma unroll
    for (int i = 0; i < 16; ++i) {
        int node = n0 + oi0 + i;
        if (node < NNODES) {
            float4 o;
            o.x = fmaxf(oacc[i][0] + bv.x, 0.f);
            o.y = fmaxf(oacc[i][1] + bv.y, 0.f);
            o.z = fmaxf(oacc[i][2] + bv.z, 0.f);
            o.w = fmaxf(oacc[i][3] + bv.w, 0.f);
            *(float4*)(Xout + ((size_t)b * NNODES + node) * d_out_total + c0 + cx * 4) = o;
        }
    }
}

// ---------------------------------------------------------------------------
// Global mean pool over nodes: gf[b,c] = mean_n X3[b,n,c]
// ---------------------------------------------------------------------------
__global__ __launch_bounds__(128) void pool_kernel(
    const float* __restrict__ X3, float* __restrict__ gf_out)
{
    int b = blockIdx.x, c = threadIdx.x;   // 128 threads
    const float* p = X3 + (size_t)b * NNODES * 128 + c;
    float s0 = 0.f, s1 = 0.f, s2 = 0.f, s3 = 0.f;
    for (int n = 0; n < NNODES; n += 4) {
        s0 += p[(n + 0) * 128];
        s1 += p[(n + 1) * 128];
        s2 += p[(n + 2) * 128];
        s3 += p[(n + 3) * 128];
    }
    float s = (s0 + s1) + (s2 + s3);
    gf_out[b * 128 + c] = s / 468.0f;
}

// ---------------------------------------------------------------------------
// Head: features = relu(gf @ Wf + bf); out = features @ Wc + bc
// ---------------------------------------------------------------------------
__global__ __launch_bounds__(512) void head_kernel(
    const float* __restrict__ gf_all, const float* __restrict__ Wf,
    const float* __restrict__ bf, const float* __restrict__ Wc,
    const float* __restrict__ bc, float* __restrict__ dout)
{
    __shared__ float gfs[128];
    __shared__ float feats[512];
    int b = blockIdx.x, t = threadIdx.x;
    if (t < 128) gfs[t] = gf_all[b * 128 + t];
    __syncthreads();
    float a = bf[t];
    for (int k = 0; k < 128; ++k) a += gfs[k] * Wf[k * 512 + t];
    a = fmaxf(a, 0.f);
    dout[256 + b * 512 + t] = a;   // features region
    feats[t] = a;
    __syncthreads();
    if (t < 64) {
        float s0 = 0.f, s1 = 0.f;
        for (int c = t; c < 512; c += 64) {
            float f = feats[c];
            s0 += f * Wc[c * 2 + 0];
            s1 += f * Wc[c * 2 + 1];
        }
        #pragma unroll
        for (int off = 32; off; off >>= 1) {
            s0 += __shfl_down(s0, off);
            s1 += __shfl_down(s1, off);
        }
        if (t == 0) {
            dout[b * 2 + 0] = s0 + bc[0];
            dout[b * 2 + 1] = s1 + bc[1];
        }
    }
}

// ---------------------------------------------------------------------------
extern "C" void kernel_launch(void* const* d_in, const int* in_sizes, int n_in,
                              void* d_out, int out_size, void* d_ws, size_t ws_size,
                              hipStream_t stream)
{
    const float* landmarks = (const float*)d_in[0];
    const float* W_enc     = (const float*)d_in[1];
    const float* b_enc     = (const float*)d_in[2];
    const float* W1        = (const float*)d_in[3];
    const float* b1        = (const float*)d_in[4];
    const float* W2        = (const float*)d_in[5];
    const float* b2        = (const float*)d_in[6];
    const float* W3        = (const float*)d_in[7];
    const float* b3        = (const float*)d_in[8];
    const float* W_fus     = (const float*)d_in[9];
    const float* b_fus     = (const float*)d_in[10];
    const float* W_cls     = (const float*)d_in[11];
    const float* b_cls     = (const float*)d_in[12];
    float* out = (float*)d_out;

    // workspace ping-pong: bufA holds X0 then X2; bufB holds X1 then X3
    char* ws = (char*)d_ws;
    float* bufA = (float*)ws;                               // 61,341,696 B region
    float* bufB = (float*)(ws + (size_t)61341696);          // 30,670,848 B region
    float* X0 = bufA;
    float* X1 = bufB;
    float* X2 = bufA;
    float* X3 = bufB;

    // d_out layout: [0,256) output | [256,65792) features | [65792,82176) graph_features
    float* gf = out + 65792;

    enc_kernel<<<14976, 256, 0, stream>>>(landmarks, W_enc, b_enc, X0);
    gcn_layer<64> <<<dim3(4, 128, 1), 256, 0, stream>>>(X0, W1, b1, X1, 128);
    gcn_layer<128><<<dim3(4, 128, 2), 256, 0, stream>>>(X1, W2, b2, X2, 256);
    gcn_layer<256><<<dim3(4, 128, 1), 256, 0, stream>>>(X2, W3, b3, X3, 128);
    pool_kernel<<<128, 128, 0, stream>>>(X3, gf);
    head_kernel<<<128, 512, 0, stream>>>(gf, W_fus, b_fus, W_cls, b_cls, out);
}